// Round 8
// baseline (529.507 us; speedup 1.0000x reference)
//
#include <hip/hip_runtime.h>
#include <stdint.h>

// Vector quantizer, bit-exact emulation of the numpy-f32 reference pipeline:
//   Sx[n] = np.sum(x_flat*x_flat, 1)   (numpy pairwise_sum, n=256)
//   M     = x_flat @ cb.T              (BLAS: sequential FMA over c ascending)
//   dist  = fl(fl(Sx - 2M) + Se),  idx = argmin (first min)
// x (16,256,1500) f32, codebook (2048,256) f32.
// out = [quantized (B,C,T) | indices (B,1,T) as float | loss] f32.
//
// Round 8 structure: lane<->row, block<->32 codes (cb stream SHARED by all
// waves -> sL1-hot s_loads feeding v_fma's SGPR operand), c-chunk outer /
// codes inner so the lane's 16-c row chunk lives in registers (xv[4]) and is
// reused across all 32 codes: 4 ds_read_b128 per 512 FMAs. acc[32] fully
// unrolled (static indices). Double-buffered x staging via pre-swizzled
// global_load_lds issued before each ~1000-cyc FMA phase. No merge phase:
// lane owns its row for the block's k-slice -> one u64 atomicMin per lane.

#define B_DIM 16
#define C_DIM 256
#define T_DIM 1500
#define K_CODES 2048
#define N_ROWS (B_DIM * T_DIM)               // 24000
#define TOTAL_ELEMS (B_DIM * C_DIM * T_DIM)  // 6144000

#define RPB 256      // rows per block (lane <-> row)
#define KPB 32       // codes per block
#define CCH 16       // c per chunk
#define NCH (C_DIM / CCH)    // 16 chunks
#define OT 64        // t per output block

__device__ __forceinline__ void gl_lds16(const float* g, float* l) {
    __builtin_amdgcn_global_load_lds(
        (const __attribute__((address_space(1))) void*)(uintptr_t)g,
        (__attribute__((address_space(3))) void*)(uintptr_t)l, 16, 0, 0);
}

// ---------------- kernel T: x (B,C,T) -> xT (B,T,C) in d_out scratch --------
__global__ __launch_bounds__(256) void vq_transpose(const float* __restrict__ x,
                                                    float* __restrict__ xT) {
    __shared__ float tile[32][33];
    const int b = blockIdx.z;
    const int t0 = blockIdx.x * 32;
    const int c0 = blockIdx.y * 32;
    const int tx = threadIdx.x & 31;
    const int ty = threadIdx.x >> 5;          // 0..7
#pragma unroll
    for (int q = 0; q < 4; ++q) {
        const int c = c0 + ty * 4 + q;
        int t = t0 + tx; if (t >= T_DIM) t = T_DIM - 1;
        tile[ty * 4 + q][tx] = x[((size_t)b * C_DIM + c) * T_DIM + t];
    }
    __syncthreads();
#pragma unroll
    for (int q = 0; q < 4; ++q) {
        const int t = t0 + ty * 4 + q;
        if (t < T_DIM)
            xT[((size_t)b * T_DIM + t) * C_DIM + c0 + tx] = tile[tx][ty * 4 + q];
    }
}

// ---------------- kernel A: Se[k] = np-pairwise sum of cb row squares -------
__global__ __launch_bounds__(256) void vq_se(const float* __restrict__ cb,
                                             float* __restrict__ Se) {
    const int k = blockIdx.x * 256 + threadIdx.x;
    if (k >= K_CODES) return;
    const float* row = cb + (size_t)k * C_DIM;
    float h[2];
#pragma unroll
    for (int half = 0; half < 2; ++half) {
        const float* a = row + half * 128;
        float r[8];
#pragma unroll
        for (int j = 0; j < 8; ++j) r[j] = __fmul_rn(a[j], a[j]);
        for (int i = 8; i < 128; i += 8)
#pragma unroll
            for (int j = 0; j < 8; ++j)
                r[j] = __fadd_rn(r[j], __fmul_rn(a[i + j], a[i + j]));
        h[half] = __fadd_rn(
            __fadd_rn(__fadd_rn(r[0], r[1]), __fadd_rn(r[2], r[3])),
            __fadd_rn(__fadd_rn(r[4], r[5]), __fadd_rn(r[6], r[7])));
    }
    Se[k] = __fadd_rn(h[0], h[1]);
}

// ---------------- kernel B: Sx[n] from xT rows (same pairwise order) --------
__global__ __launch_bounds__(256) void vq_sx(const float* __restrict__ xT,
                                             float* __restrict__ Sx) {
    const int n = blockIdx.x * 256 + threadIdx.x;
    if (n >= N_ROWS) return;
    const float* row = xT + (size_t)n * C_DIM;
    float h[2];
#pragma unroll
    for (int half = 0; half < 2; ++half) {
        const float* a = row + half * 128;
        float r[8];
#pragma unroll
        for (int j = 0; j < 8; ++j) r[j] = __fmul_rn(a[j], a[j]);
        for (int i = 8; i < 128; i += 8)
#pragma unroll
            for (int j = 0; j < 8; ++j)
                r[j] = __fadd_rn(r[j], __fmul_rn(a[i + j], a[i + j]));
        h[half] = __fadd_rn(
            __fadd_rn(__fadd_rn(r[0], r[1]), __fadd_rn(r[2], r[3])),
            __fadd_rn(__fadd_rn(r[4], r[5]), __fadd_rn(r[6], r[7])));
    }
    Sx[n] = __fadd_rn(h[0], h[1]);
}

// ---------------- kernel I: init u64 argmin slots ---------------------------
__global__ void vq_init(unsigned long long* __restrict__ slots) {
    const int n = blockIdx.x * 256 + threadIdx.x;
    if (n < N_ROWS) slots[n] = ~0ull;
}

// ---- stage one 256-row x 16-c chunk into BUF (source pre-swizzled so the
// linear gl_lds dest ends with slot s holding granule g = s ^ ((row>>1)&3);
// read-side swizzle spreads the stride-64B row reads across all 8 bank quads)
#define STAGE(BUF, CH) do {                                                    \
    _Pragma("unroll")                                                          \
    for (int p_ = 0; p_ < 4; ++p_) {                                           \
        const int F_ = p_ * 256 + tid;                                         \
        const int r_ = F_ >> 2, s_ = F_ & 3;                                   \
        const int g_ = s_ ^ ((r_ >> 1) & 3);                                   \
        int t_ = t0 + r_; if (t_ >= T_DIM) t_ = T_DIM - 1;                     \
        gl_lds16(xTb + (size_t)t_ * C_DIM + (CH) * CCH + g_ * 4,               \
                 &BUF[F_ * 4]);                                                \
    } } while (0)

// ---------------- kernel C: fused GEMM + argmin (bit-exact np-f32) ----------
// grid (64 k-slices, 6 row-blocks, 16 b), 256 threads = 4 waves.
__global__ __launch_bounds__(256, 4) void vq_argmin(
    const float* __restrict__ xT, const float* __restrict__ cb,
    const float* __restrict__ Se, const float* __restrict__ Sx,
    unsigned long long* __restrict__ slots) {
    __shared__ float xs0[RPB * CCH];    // 16 KB
    __shared__ float xs1[RPB * CCH];    // 16 KB

    const int tid = threadIdx.x;
    const int k0 = blockIdx.x * KPB;
    const int t0 = blockIdx.y * RPB;
    const int b = blockIdx.z;

    const float* xTb = xT + (size_t)b * T_DIM * C_DIM;
    const float* cbb = cb + (size_t)k0 * C_DIM;

    float acc[KPB];
#pragma unroll
    for (int j = 0; j < KPB; ++j) acc[j] = 0.f;

    STAGE(xs0, 0);
    __syncthreads();

    const int sw = (tid >> 1) & 3;      // this lane's read swizzle key

#pragma unroll 1
    for (int ch = 0; ch < NCH; ++ch) {
        // prefetch next chunk into the other buffer (drained at end barrier)
        if (ch + 1 < NCH) {
            if (ch & 1) STAGE(xs0, ch + 1);
            else        STAGE(xs1, ch + 1);
        }
        // own row chunk -> registers (4 swizzled ds_read_b128, 8-quad spread)
        const float* xbuf = (ch & 1) ? xs1 : xs0;
        float4 xv[4];
#pragma unroll
        for (int g = 0; g < 4; ++g)
            xv[g] = *reinterpret_cast<const float4*>(
                &xbuf[tid * CCH + ((g ^ sw) << 2)]);
        // 32 codes x 16 c; cb values are block-uniform -> SGPR operand FMAs
#pragma unroll
        for (int j = 0; j < KPB; ++j) {
            const float* cj = cbb + (size_t)j * C_DIM + ch * CCH;
            const float4 c0 = *reinterpret_cast<const float4*>(cj);
            const float4 c1 = *reinterpret_cast<const float4*>(cj + 4);
            const float4 c2 = *reinterpret_cast<const float4*>(cj + 8);
            const float4 c3 = *reinterpret_cast<const float4*>(cj + 12);
            acc[j] = fmaf(xv[0].x, c0.x, acc[j]);
            acc[j] = fmaf(xv[0].y, c0.y, acc[j]);
            acc[j] = fmaf(xv[0].z, c0.z, acc[j]);
            acc[j] = fmaf(xv[0].w, c0.w, acc[j]);
            acc[j] = fmaf(xv[1].x, c1.x, acc[j]);
            acc[j] = fmaf(xv[1].y, c1.y, acc[j]);
            acc[j] = fmaf(xv[1].z, c1.z, acc[j]);
            acc[j] = fmaf(xv[1].w, c1.w, acc[j]);
            acc[j] = fmaf(xv[2].x, c2.x, acc[j]);
            acc[j] = fmaf(xv[2].y, c2.y, acc[j]);
            acc[j] = fmaf(xv[2].z, c2.z, acc[j]);
            acc[j] = fmaf(xv[2].w, c2.w, acc[j]);
            acc[j] = fmaf(xv[3].x, c3.x, acc[j]);
            acc[j] = fmaf(xv[3].y, c3.y, acc[j]);
            acc[j] = fmaf(xv[3].z, c3.z, acc[j]);
            acc[j] = fmaf(xv[3].w, c3.w, acc[j]);
        }
        __syncthreads();    // chunk done; next-stage loads long since issued
    }

    // ---- score: dist = fl(fl(Sx - 2*M) + Se); first-min (j ascending)
    int myt = t0 + tid; if (myt >= T_DIM) myt = T_DIM - 1;
    const float sxv = Sx[b * T_DIM + myt];
    float m1 = 1e30f;
    int k1 = 0;
#pragma unroll
    for (int j = 0; j < KPB; ++j) {
        const float se = Se[k0 + j];                 // uniform -> s_load
        const float s = __fadd_rn(
            __fsub_rn(sxv, __fmul_rn(2.0f, acc[j])), se);
        if (s < m1) { m1 = s; k1 = k0 + j; }
    }
    if (t0 + tid < T_DIM) {
        const unsigned long long pack =
            ((unsigned long long)__float_as_uint(m1) << 32) | (unsigned)k1;
        atomicMin(slots + b * T_DIM + t0 + tid, pack);
    }
}

// ---------------- kernel D: gather + STE output + indices + loss partials ---
__global__ __launch_bounds__(256) void vq_output(
    const float* __restrict__ x, const float* __restrict__ cb,
    const unsigned long long* __restrict__ slots, float* __restrict__ out,
    float* __restrict__ partials) {
    const int tid = threadIdx.x;
    const int b = blockIdx.y;
    const int t0 = blockIdx.x * OT;
    __shared__ int idxs[OT];
    if (tid < OT) {
        const int t = t0 + tid;
        if (t < T_DIM) {
            const int id = (int)(unsigned)(slots[b * T_DIM + t] & 0xffffffffull);
            idxs[tid] = id;
            out[(size_t)TOTAL_ELEMS + b * T_DIM + t] = (float)id;   // indices
        }
    }
    __syncthreads();
    const int ti = tid & 63;
    const int cq = tid >> 6;       // 0..3
    const int t = t0 + ti;
    float lsum = 0.f;
    if (t < T_DIM) {
        const int id = idxs[ti];
        for (int c0 = 0; c0 < C_DIM; c0 += 4) {
            const int c = c0 + cq;
            const size_t off = (size_t)(b * C_DIM + c) * T_DIM + t;
            const float xv = x[off];
            const float q = cb[(size_t)id * C_DIM + c];
            out[off] = __fadd_rn(xv, __fsub_rn(q, xv));   // STE, np-exact
            const float d = __fsub_rn(q, xv);
            lsum = fmaf(d, d, lsum);
        }
    }
#pragma unroll
    for (int off = 32; off; off >>= 1) lsum += __shfl_down(lsum, off, 64);
    __shared__ float wsum[4];
    if ((tid & 63) == 0) wsum[tid >> 6] = lsum;
    __syncthreads();
    if (tid == 0)
        partials[blockIdx.y * gridDim.x + blockIdx.x] =
            wsum[0] + wsum[1] + wsum[2] + wsum[3];
}

// ---------------- kernel E: final loss reduce -------------------------------
__global__ void vq_loss(const float* __restrict__ partials, int nparts,
                        float* __restrict__ out) {
    __shared__ float red[256];
    float s = 0.f;
    for (int i = threadIdx.x; i < nparts; i += 256) s += partials[i];
    red[threadIdx.x] = s;
    __syncthreads();
    for (int off = 128; off; off >>= 1) {
        if (threadIdx.x < off) red[threadIdx.x] += red[threadIdx.x + off];
        __syncthreads();
    }
    if (threadIdx.x == 0)
        out[(size_t)TOTAL_ELEMS + N_ROWS] = red[0] * (1.0f / (float)TOTAL_ELEMS);
}

// ---------------- launch -----------------------------------------------------
extern "C" void kernel_launch(void* const* d_in, const int* in_sizes, int n_in,
                              void* d_out, int out_size, void* d_ws, size_t ws_size,
                              hipStream_t stream) {
    const float* x = (const float*)d_in[0];
    const float* cb = (const float*)d_in[1];
    float* out = (float*)d_out;

    // xT scratch lives in d_out[0 .. 6144000) (overwritten by vq_output later)
    float* xT = out;

    // ws layout (bytes): Se 8K | Sx 96000 | slots (u64, 8-aligned) | partials
    float* Se = (float*)d_ws;
    float* Sx = Se + K_CODES;
    unsigned long long* slots =
        (unsigned long long*)((char*)d_ws + ((8192 + 96000 + 7) & ~7ull));
    float* partials = (float*)(slots + N_ROWS);

    vq_transpose<<<dim3(47, 8, B_DIM), dim3(256), 0, stream>>>(x, xT);
    vq_se<<<dim3(K_CODES / 256), dim3(256), 0, stream>>>(cb, Se);
    vq_sx<<<dim3((N_ROWS + 255) / 256), dim3(256), 0, stream>>>(xT, Sx);
    vq_init<<<dim3((N_ROWS + 255) / 256), dim3(256), 0, stream>>>(slots);
    vq_argmin<<<dim3(K_CODES / KPB, (T_DIM + RPB - 1) / RPB, B_DIM),
                dim3(256), 0, stream>>>(xT, cb, Se, Sx, slots);
    vq_output<<<dim3((T_DIM + OT - 1) / OT, B_DIM), dim3(256), 0, stream>>>(
        x, cb, slots, out, partials);
    vq_loss<<<dim3(1), dim3(256), 0, stream>>>(
        partials, (T_DIM + OT - 1) / OT * B_DIM, out);
}